// Round 5
// baseline (210.050 us; speedup 1.0000x reference)
//
#include <hip/hip_runtime.h>
#include <stdint.h>

// CropConv implicit GEMM (bf16 MFMA, fp32 accum).
//   M=64 (oc), K=576 (ic*3*3), N=262144 (b*h*w)
// v4 (resubmit; round-4 bench died on infra before dispatch):
// concurrency push. v3 post-mortem: grid 1024 = 4 blocks/CU total ->
// time-avg residency ~2 blocks (occupancy 21%) regardless of LDS size.
//   - block re-tiled 4h x 32w x 64oc, 256 thr; LDS 6r x 34c x 64ic bf16
//     = 25.5 KiB -> 6 blocks/CU capacity (24 waves/CU = 75%); grid 2048
//     = 8 blocks/CU of work -> sustained ~4-5 resident.
//   - waves split by (oc-half x h-pair): 2 A-frags x 4 B-frags = 8 MFMA/group
//     -> A:MFMA ratio unchanged vs v3; acc halves to 32 VGPR (6 waves/SIMD
//     needs <=85 VGPR; v3 measured 84 with 64-reg acc).
//   - staging vectorized: float4 global loads (4 cols at once), per-thread
//     loads 96 scalar -> ~24 vector; halo cols (96 uint4) keep scalar gather.
//   - swizzle slot = (j + c) & 7, row stride 272 = 0 mod 8 (v2/v3 measured
//     0 conflicts with this family).
// Weights: pre-pass -> bf16 workspace [kk][ch][i][lane] (72 KiB), A-loads
// lane-consecutive uint4 -> coalesced, L2-hot.
// Fallback: if ws_size < 73728, launch the v1 fully-fused kernel.

#define B_ 16
#define C_ 64
#define H_ 128
#define W_ 128

#define TROWS 6
#define TCOLS 34
#define XLDS_U4 (TROWS * TCOLS * 8)   // 1632 uint4 = 25.5 KiB

typedef float f32x4 __attribute__((ext_vector_type(4)));
typedef short bf16x8 __attribute__((ext_vector_type(8)));

__device__ inline unsigned short f2bf(float f) {
    union { float f; uint32_t u; } v; v.f = f;
    uint32_t u = v.u + 0x7FFF + ((v.u >> 16) & 1);   // RNE
    return (unsigned short)(u >> 16);
}

// ---- pre-pass: weights [oc][ic][3][3] fp32 -> bf16 [kk][ch][i][lane][e] ----
// element L = (((kk*2+ch)*4 + i)*64 + lane)*8 + e  holds
//   wgt[oc = i*16 + (lane&15)][ic = ch*32 + (lane>>4)*8 + e][kk]
__global__ __launch_bounds__(256) void xform_weight(
    const float* __restrict__ wgt, uint16_t* __restrict__ Wb)
{
    int L = blockIdx.x * 256 + threadIdx.x;       // < 36864
    int e    = L & 7;
    int lane = (L >> 3) & 63;
    int i    = (L >> 9) & 3;
    int ch   = (L >> 11) & 1;
    int kk   = L >> 12;
    int oc   = i * 16 + (lane & 15);
    int ic   = ch * 32 + (lane >> 4) * 8 + e;
    Wb[L] = f2bf(wgt[((size_t)oc * 64 + ic) * 9 + kk]);
}

// ---- main: 4h x 32w x 64oc block ----
// grid 2048 = 16 b x 32 ht x 4 wt; block 256 = 4 waves;
// wave wv: ohalf = wv&1 (oc 32*ohalf..+31), hbase = (wv>>1)*2 (rows 0-1 / 2-3).
// LDS tile: [r:6][c:34][slot:8] uint4, slot = (j + c) & 7, j = ic>>3.
// tile col c <-> global w = wt*32 + c - 1 (cols 0 and 33 are the w-halo).
__global__ __launch_bounds__(256, 6) void conv_main(
    const uint4* __restrict__ Wq,    // [9][2][4][64] uint4 bf16
    const float* __restrict__ x,     // [16][64][128][128] fp32
    float* __restrict__ out)         // [16][64][128][128] fp32
{
    __shared__ uint4 lds[XLDS_U4];   // 25.5 KiB

    const int t    = threadIdx.x;
    const int lane = t & 63;
    const int wv   = t >> 6;
    const int n    = lane & 15;
    const int q    = lane >> 4;

    // XCD-contiguous remap (2048 = 8 * 256, bijective): each XCD gets 2 batches
    const int d    = blockIdx.x;
    const int orig = (d & 7) * 256 + (d >> 3);
    const int wt   = orig & 3;                    // w-tile: w = wt*32 .. +31
    const int ht   = (orig >> 2) & 31;
    const int b    = orig >> 7;
    const int h0   = ht * 4;

    // ---- stage input: fp32 NCHW -> swizzled bf16 tile ----
    // main cols 1..32 via float4 loads: thread = (c4: 8) x (j: 8) x (rr: 4);
    // rr handles row rr, and row rr+4 if rr < 2  (rows 0..5 covered once).
    {
        const int c4    = t & 7;                  // col-quad
        const int j     = (t >> 3) & 7;           // ic octet
        const int rr    = t >> 6;                 // 0..3
        const int cbase = 1 + c4 * 4;             // tile col base (1..29)
        const int wg0   = wt * 32 + c4 * 4;       // global w base (always valid)

        #pragma unroll
        for (int pass = 0; pass < 2; ++pass) {
            const int r = rr + pass * 4;
            if (pass == 1 && rr >= 2) break;      // rows 4,5 only from rr=0,1
            const int h = h0 - 1 + r;             // -1..128
            if (h < 0 || h >= H_) {               // halo row: zero
                uint4 z; z.x = z.y = z.z = z.w = 0;
                #pragma unroll
                for (int cc = 0; cc < 4; ++cc)
                    lds[(r * TCOLS + cbase + cc) * 8 + ((j + cbase + cc) & 7)] = z;
            } else {
                const float* src =
                    x + (((size_t)(b * C_ + j * 8)) * H_ + h) * W_ + wg0;
                f32x4 f[8];
                #pragma unroll
                for (int e = 0; e < 8; ++e)
                    f[e] = *(const f32x4*)(src + (size_t)e * (H_ * W_));
                #pragma unroll
                for (int cc = 0; cc < 4; ++cc) {
                    uint32_t u[4];
                    #pragma unroll
                    for (int p = 0; p < 4; ++p)
                        u[p] = (uint32_t)f2bf(f[2 * p][cc]) |
                               ((uint32_t)f2bf(f[2 * p + 1][cc]) << 16);
                    lds[(r * TCOLS + cbase + cc) * 8 + ((j + cbase + cc) & 7)] =
                        *(const uint4*)u;
                }
            }
        }

        // halo cols 0 and 33: 96 uint4, threads 128..223, scalar ic-gather
        if (t >= 128 && t < 224) {
            const int u   = t - 128;              // 0..95
            const int ce  = (u >= 48) ? (TCOLS - 1) : 0;
            const int rem = u - (u >= 48 ? 48 : 0);
            const int r   = rem >> 3;             // 0..5
            const int jj  = rem & 7;
            const int h   = h0 - 1 + r;
            const int wg  = wt * 32 + ce - 1;     // -1 | 31|32|63|64|95|96 | 128
            uint4 val; val.x = val.y = val.z = val.w = 0;
            if (h >= 0 && h < H_ && wg >= 0 && wg < W_) {
                const float* src =
                    x + (((size_t)(b * C_ + jj * 8)) * H_ + h) * W_ + wg;
                uint32_t uu[4];
                #pragma unroll
                for (int p = 0; p < 4; ++p) {
                    float v0 = src[(size_t)(2 * p)     * (H_ * W_)];
                    float v1 = src[(size_t)(2 * p + 1) * (H_ * W_)];
                    uu[p] = (uint32_t)f2bf(v0) | ((uint32_t)f2bf(v1) << 16);
                }
                val = *(const uint4*)uu;
            }
            lds[(r * TCOLS + ce) * 8 + ((jj + ce) & 7)] = val;
        }
    }
    __syncthreads();

    // ---- K-loop: 18 groups (3 kh x 3 kw x 2 ch), 2x4 MFMA tiles per wave ----
    f32x4 acc[2][4];
    #pragma unroll
    for (int i = 0; i < 2; ++i)
        #pragma unroll
        for (int f = 0; f < 4; ++f)
            acc[i][f] = (f32x4){0.f, 0.f, 0.f, 0.f};

    const int ohalf = wv & 1;             // oc half
    const int hbase = (wv >> 1) * 2;      // output rows hbase, hbase+1

    #pragma unroll
    for (int kh = 0; kh < 3; ++kh) {
        #pragma unroll
        for (int kw = 0; kw < 3; ++kw) {
            const int kk = kh * 3 + kw;
            #pragma unroll
            for (int ch = 0; ch < 2; ++ch) {
                bf16x8 a[2], bb[4];
                #pragma unroll
                for (int i = 0; i < 2; ++i)
                    a[i] = __builtin_bit_cast(bf16x8,
                        Wq[((kk * 2 + ch) * 4 + ohalf * 2 + i) * 64 + lane]);
                #pragma unroll
                for (int f = 0; f < 4; ++f) {
                    const int hh  = f >> 1, tt = f & 1;
                    const int row = hbase + hh + kh;          // 0..5
                    const int ct  = tt * 16 + n + kw;         // 0..33
                    const int idx = (row * TCOLS + ct) * 8 + ((ch * 4 + q + ct) & 7);
                    bb[f] = __builtin_bit_cast(bf16x8, lds[idx]);
                }
                #pragma unroll
                for (int i = 0; i < 2; ++i)
                    #pragma unroll
                    for (int f = 0; f < 4; ++f)
                        acc[i][f] = __builtin_amdgcn_mfma_f32_16x16x32_bf16(
                            a[i], bb[f], acc[i][f], 0, 0, 0);
            }
        }
    }

    // ---- epilogue: oc = ohalf*32 + i*16 + q*4 + r, crop mask ----
    #pragma unroll
    for (int f = 0; f < 4; ++f) {
        const int hh = f >> 1, tt = f & 1;
        const int h  = h0 + hbase + hh;
        const int w0 = wt * 32 + tt * 16 + n;
        const bool zz = (h >= 44 && h < 84) && (w0 >= 44 && w0 < 84);
        #pragma unroll
        for (int i = 0; i < 2; ++i) {
            #pragma unroll
            for (int r = 0; r < 4; ++r) {
                const int oc = ohalf * 32 + i * 16 + q * 4 + r;
                out[(((size_t)b * C_ + oc) * H_ + h) * W_ + w0] =
                    zz ? 0.f : acc[i][f][r];
            }
        }
    }
}

// ================= fallback: fully-fused single kernel (v1, 88.5 us) ========
#define WLDS_U4 4608   // 9*2*4*64 uint4 = 72 KiB weights
#define FXLDS_U4 4096  // 4*128*8 uint4 = 64 KiB input tile

__global__ __launch_bounds__(256, 1) void conv_fused(
    const float* __restrict__ x,
    const float* __restrict__ wgt,
    float* __restrict__ out)
{
    __shared__ uint4 lds[WLDS_U4 + FXLDS_U4];          // 136 KiB
    uint16_t* lds16 = (uint16_t*)lds;

    const int t    = threadIdx.x;
    const int lane = t & 63;
    const int wv   = t >> 6;
    const int n    = lane & 15;
    const int q    = lane >> 4;

    const int d    = blockIdx.x;
    const int orig = (d & 7) * 128 + (d >> 3);
    const int b    = orig >> 6;
    const int h0   = (orig & 63) * 2;

    #pragma unroll
    for (int p = 0; p < 2; ++p) {
        const int a_  = t + 256 * p;
        const int oc  = a_ >> 3;
        const int oct = a_ & 7;
        const float* src = wgt + (size_t)oc * 576 + (size_t)oct * 72;
        f32x4 w4[18];
        #pragma unroll
        for (int j = 0; j < 18; ++j) w4[j] = ((const f32x4*)src)[j];
        const int ch = oct >> 2, qq = oct & 3;
        const int ii = oc >> 4,  nn = oc & 15;
        #pragma unroll
        for (int kk = 0; kk < 9; ++kk) {
            #define WELEM(e) ((uint32_t)f2bf(w4[((e)*9 + kk) >> 2][((e)*9 + kk) & 3]))
            uint4 val;
            val.x = WELEM(0) | (WELEM(1) << 16);
            val.y = WELEM(2) | (WELEM(3) << 16);
            val.z = WELEM(4) | (WELEM(5) << 16);
            val.w = WELEM(6) | (WELEM(7) << 16);
            #undef WELEM
            lds[((kk * 2 + ch) * 4 + ii) * 64 + qq * 16 + nn] = val;
        }
    }

    {
        const int ic    = t >> 2;
        const int w0    = (t & 3) * 32;
        const int jslot = ic >> 3;
        const int esub  = ic & 7;
        #pragma unroll
        for (int r = 0; r < 4; ++r) {
            const int h = h0 - 1 + r;
            if (h < 0 || h >= H_) {
                uint4 z; z.x = z.y = z.z = z.w = 0;
                #pragma unroll
                for (int k = 0; k < 4; ++k)
                    lds[WLDS_U4 + r * 1024 + k * 256 + t] = z;
            } else {
                const float* src =
                    x + (((size_t)(b * C_ + ic)) * H_ + h) * W_ + w0;
                f32x4 v4[8];
                #pragma unroll
                for (int j = 0; j < 8; ++j) v4[j] = ((const f32x4*)src)[j];
                #pragma unroll
                for (int k = 0; k < 32; ++k) {
                    const int c    = w0 + k;
                    const int slot = (jslot + c) & 7;
                    lds16[WLDS_U4 * 8 + ((r * 128 + c) * 8 + slot) * 8 + esub] =
                        f2bf(v4[k >> 2][k & 3]);
                }
            }
        }
    }
    __syncthreads();

    f32x4 acc[4][4];
    #pragma unroll
    for (int i = 0; i < 4; ++i)
        #pragma unroll
        for (int tt = 0; tt < 4; ++tt)
            acc[i][tt] = (f32x4){0.f, 0.f, 0.f, 0.f};

    const int wb = (wv & 1) * 64;
    const uint4* Wl = lds;
    const uint4* Xl = lds + WLDS_U4;
    const bool lz = (wb + n) == 0;
    const bool rz = (wb + n) == 79;
    const bf16x8 zfrag = 0;

    #pragma unroll
    for (int kh = 0; kh < 3; ++kh) {
        const int row = (wv >> 1) + kh;
        #pragma unroll
        for (int kw = 0; kw < 3; ++kw) {
            const int kk = kh * 3 + kw;
            #pragma unroll
            for (int ch = 0; ch < 2; ++ch) {
                bf16x8 a[4], bb[4];
                #pragma unroll
                for (int i = 0; i < 4; ++i)
                    a[i] = __builtin_bit_cast(bf16x8,
                        Wl[((kk * 2 + ch) * 4 + i) * 64 + lane]);
                #pragma unroll
                for (int tt = 0; tt < 4; ++tt) {
                    int c   = wb + tt * 16 + n + kw - 1;
                    int cc  = min(max(c, 0), 127);
                    int idx = (row * 128 + cc) * 8 + ((ch * 4 + q + cc) & 7);
                    bf16x8 v = __builtin_bit_cast(bf16x8, Xl[idx]);
                    if (kw == 0 && tt == 0) v = lz ? zfrag : v;
                    if (kw == 2 && tt == 3) v = rz ? zfrag : v;
                    bb[tt] = v;
                }
                #pragma unroll
                for (int i = 0; i < 4; ++i)
                    #pragma unroll
                    for (int tt = 0; tt < 4; ++tt)
                        acc[i][tt] = __builtin_amdgcn_mfma_f32_16x16x32_bf16(
                            a[i], bb[tt], acc[i][tt], 0, 0, 0);
            }
        }
    }

    const int  h  = h0 + (wv >> 1);
    const bool hz = (h >= 44 && h < 84);
    #pragma unroll
    for (int i = 0; i < 4; ++i) {
        #pragma unroll
        for (int tt = 0; tt < 4; ++tt) {
            const int  w0 = wb + tt * 16 + n;
            const bool zz = hz && (w0 >= 44 && w0 < 84);
            #pragma unroll
            for (int r = 0; r < 4; ++r) {
                const int oc = i * 16 + q * 4 + r;
                out[(((size_t)b * C_ + oc) * H_ + h) * W_ + w0] =
                    zz ? 0.f : acc[i][tt][r];
            }
        }
    }
}

extern "C" void kernel_launch(void* const* d_in, const int* in_sizes, int n_in,
                              void* d_out, int out_size, void* d_ws, size_t ws_size,
                              hipStream_t stream) {
    const float* x   = (const float*)d_in[0];
    const float* wgt = (const float*)d_in[1];
    float* out       = (float*)d_out;

    const size_t W_BYTES = 9 * 2 * 4 * 64 * 16;   // 73,728
    if (ws_size >= W_BYTES) {
        uint16_t* Wb = (uint16_t*)d_ws;
        xform_weight<<<dim3(144), dim3(256), 0, stream>>>(wgt, Wb);
        conv_main<<<dim3(2048), dim3(256), 0, stream>>>(
            (const uint4*)Wb, x, out);
    } else {
        conv_fused<<<dim3(1024), dim3(256), 0, stream>>>(x, wgt, out);
    }
}

// Round 6
// 135.831 us; speedup vs baseline: 1.5464x; 1.5464x over previous
//
#include <hip/hip_runtime.h>
#include <stdint.h>

// CropConv implicit GEMM (bf16 MFMA, fp32 accum).
//   M=64 (oc), K=576 (ic*3*3), N=262144 (b*h*w)
// v5: traffic fix. v4 post-mortem: occupancy hit 51% but FETCH 39->133MB,
// WRITE 66->223MB (narrow 32-w blocks => 128B-granular rows, 64B sector
// writes + 768 halo line-touches/block => partial-line RMW + L3 thrash);
// kernel became HBM-bound at 3 TB/s on 365MB of amplified traffic.
//   - block = 1h x 128w x 64oc (FULL ROW): w-halo == image pad == zero ->
//     NO halo reads at all; every global read is a full 512B row slice and
//     every (oc,h) write is 512B contiguous per block (= v2/v3's measured-
//     clean access regime: FETCH 34-39MB, WRITE 66MB).
//   - LDS 3r x 130c x 64ic bf16 = 48.75 KiB -> 3 blocks/CU; grid 2048 =
//     8 blocks/CU of work (deep queue; v3's tail problem addressed).
//   - wave split oc-half x w-half: 2 A-frags x 4 B-frags = 8 MFMA/group,
//     acc[2][4] = 32 VGPR.
//   - swizzle slot = (j + c) & 7, row stride 1040 = 0 mod 8 (same family
//     v2/v3 measured 0 conflicts).
//   - XCD remap: consecutive ht on same XCD -> 3x row redundancy served
//     from L2 (~1.5MB window << 4MB).
// Weights: pre-pass -> bf16 workspace [kk][ch][i][lane] (72 KiB), A-loads
// lane-consecutive uint4 -> coalesced, L2-hot.
// Fallback: if ws_size < 73728, launch the v1 fully-fused kernel.

#define B_ 16
#define C_ 64
#define H_ 128
#define W_ 128

#define TCOLS_A 130
#define XLDS_A (3 * TCOLS_A * 8)      // 3120 uint4 = 48.75 KiB

typedef float f32x4 __attribute__((ext_vector_type(4)));
typedef short bf16x8 __attribute__((ext_vector_type(8)));

__device__ inline unsigned short f2bf(float f) {
    union { float f; uint32_t u; } v; v.f = f;
    uint32_t u = v.u + 0x7FFF + ((v.u >> 16) & 1);   // RNE
    return (unsigned short)(u >> 16);
}

// ---- pre-pass: weights [oc][ic][3][3] fp32 -> bf16 [kk][ch][i][lane][e] ----
// element L = (((kk*2+ch)*4 + i)*64 + lane)*8 + e  holds
//   wgt[oc = i*16 + (lane&15)][ic = ch*32 + (lane>>4)*8 + e][kk]
__global__ __launch_bounds__(256) void xform_weight(
    const float* __restrict__ wgt, uint16_t* __restrict__ Wb)
{
    int L = blockIdx.x * 256 + threadIdx.x;       // < 36864
    int e    = L & 7;
    int lane = (L >> 3) & 63;
    int i    = (L >> 9) & 3;
    int ch   = (L >> 11) & 1;
    int kk   = L >> 12;
    int oc   = i * 16 + (lane & 15);
    int ic   = ch * 32 + (lane >> 4) * 8 + e;
    Wb[L] = f2bf(wgt[((size_t)oc * 64 + ic) * 9 + kk]);
}

// ---- main: 1h x 128w x 64oc block ----
// grid 2048 = 16 b x 128 ht; block 256 = 4 waves;
// wave wv: ohalf = wv&1 (oc 32*ohalf..+31), whalf = wv>>1 (w 64*whalf..+63).
// LDS tile: [r:3][c:130][slot:8] uint4, slot = (j + c) & 7, j = ic>>3.
// tile col c <-> global w = c - 1 (cols 0 and 129 = image w-pad, zeroed).
__global__ __launch_bounds__(256, 3) void conv_main(
    const uint4* __restrict__ Wq,    // [9][2][4][64] uint4 bf16
    const float* __restrict__ x,     // [16][64][128][128] fp32
    float* __restrict__ out)         // [16][64][128][128] fp32
{
    __shared__ uint4 lds[XLDS_A];    // 48.75 KiB

    const int t    = threadIdx.x;
    const int lane = t & 63;
    const int wv   = t >> 6;
    const int n    = lane & 15;
    const int q    = lane >> 4;

    // XCD-contiguous remap (2048 = 8 * 256, bijective): XCD x gets orig
    // x*256..x*256+255 = 2 full batches with ht consecutive -> L2 row reuse.
    const int d    = blockIdx.x;
    const int orig = (d & 7) * 256 + (d >> 3);
    const int ht   = orig & 127;                  // output row
    const int b    = orig >> 7;

    // ---- stage input rows ht-1..ht+1, full width, fp32 -> swizzled bf16 ----
    // thread = (c4: 32 col-quads) x (j: 8 ic-octets); per row: 8 float4 loads
    // (planes j*8..j*8+7), pack, 4 swizzled uint4 LDS writes. No w-halo reads.
    {
        const int c4    = t & 31;                 // col-quad 0..31
        const int j     = t >> 5;                 // ic octet 0..7
        const int cbase = 1 + c4 * 4;             // tile col base (1..125)
        const int wg0   = c4 * 4;                 // global w base

        #pragma unroll
        for (int r = 0; r < 3; ++r) {
            const int h = ht - 1 + r;             // -1..128
            if (h < 0 || h >= H_) {               // image h-pad: zero row
                uint4 z; z.x = z.y = z.z = z.w = 0;
                #pragma unroll
                for (int cc = 0; cc < 4; ++cc)
                    lds[(r * TCOLS_A + cbase + cc) * 8 +
                        ((j + cbase + cc) & 7)] = z;
            } else {
                const float* src =
                    x + (((size_t)(b * C_ + j * 8)) * H_ + h) * W_ + wg0;
                f32x4 f[8];
                #pragma unroll
                for (int e = 0; e < 8; ++e)
                    f[e] = *(const f32x4*)(src + (size_t)e * (H_ * W_));
                #pragma unroll
                for (int cc = 0; cc < 4; ++cc) {
                    uint32_t u[4];
                    #pragma unroll
                    for (int p = 0; p < 4; ++p)
                        u[p] = (uint32_t)f2bf(f[2 * p][cc]) |
                               ((uint32_t)f2bf(f[2 * p + 1][cc]) << 16);
                    lds[(r * TCOLS_A + cbase + cc) * 8 +
                        ((j + cbase + cc) & 7)] = *(const uint4*)u;
                }
            }
        }
        // zero pad cols 0 and 129: 2 sides x 3 rows x 8 octets = 48 uint4
        if (t < 48) {
            const int ce = (t < 24) ? 0 : (TCOLS_A - 1);
            const int u  = (t < 24) ? t : t - 24;
            const int r  = u >> 3, jj = u & 7;
            uint4 z; z.x = z.y = z.z = z.w = 0;
            lds[(r * TCOLS_A + ce) * 8 + ((jj + ce) & 7)] = z;
        }
    }
    __syncthreads();

    // ---- K-loop: 18 groups (3 kh x 3 kw x 2 ch), 2x4 MFMA tiles per wave ----
    f32x4 acc[2][4];
    #pragma unroll
    for (int i = 0; i < 2; ++i)
        #pragma unroll
        for (int f = 0; f < 4; ++f)
            acc[i][f] = (f32x4){0.f, 0.f, 0.f, 0.f};

    const int ohalf = wv & 1;             // oc half
    const int wq    = (wv >> 1) * 64;     // w half base

    #pragma unroll
    for (int kh = 0; kh < 3; ++kh) {
        #pragma unroll
        for (int kw = 0; kw < 3; ++kw) {
            const int kk = kh * 3 + kw;
            #pragma unroll
            for (int ch = 0; ch < 2; ++ch) {
                bf16x8 a[2], bb[4];
                #pragma unroll
                for (int i = 0; i < 2; ++i)
                    a[i] = __builtin_bit_cast(bf16x8,
                        Wq[((kk * 2 + ch) * 4 + ohalf * 2 + i) * 64 + lane]);
                #pragma unroll
                for (int f = 0; f < 4; ++f) {
                    const int ct  = wq + f * 16 + n + kw;     // 0..129
                    const int idx = (kh * TCOLS_A + ct) * 8 +
                                    ((ch * 4 + q + ct) & 7);
                    bb[f] = __builtin_bit_cast(bf16x8, lds[idx]);
                }
                #pragma unroll
                for (int i = 0; i < 2; ++i)
                    #pragma unroll
                    for (int f = 0; f < 4; ++f)
                        acc[i][f] = __builtin_amdgcn_mfma_f32_16x16x32_bf16(
                            a[i], bb[f], acc[i][f], 0, 0, 0);
            }
        }
    }

    // ---- epilogue: oc = ohalf*32 + i*16 + q*4 + r, crop mask ----
    const int  h  = ht;
    const bool hz = (h >= 44 && h < 84);
    #pragma unroll
    for (int f = 0; f < 4; ++f) {
        const int w0 = wq + f * 16 + n;
        const bool zz = hz && (w0 >= 44 && w0 < 84);
        #pragma unroll
        for (int i = 0; i < 2; ++i) {
            #pragma unroll
            for (int r = 0; r < 4; ++r) {
                const int oc = ohalf * 32 + i * 16 + q * 4 + r;
                out[(((size_t)b * C_ + oc) * H_ + h) * W_ + w0] =
                    zz ? 0.f : acc[i][f][r];
            }
        }
    }
}

// ================= fallback: fully-fused single kernel (v1, 88.5 us) ========
#define WLDS_U4 4608   // 9*2*4*64 uint4 = 72 KiB weights
#define FXLDS_U4 4096  // 4*128*8 uint4 = 64 KiB input tile

__global__ __launch_bounds__(256, 1) void conv_fused(
    const float* __restrict__ x,
    const float* __restrict__ wgt,
    float* __restrict__ out)
{
    __shared__ uint4 lds[WLDS_U4 + FXLDS_U4];          // 136 KiB
    uint16_t* lds16 = (uint16_t*)lds;

    const int t    = threadIdx.x;
    const int lane = t & 63;
    const int wv   = t >> 6;
    const int n    = lane & 15;
    const int q    = lane >> 4;

    const int d    = blockIdx.x;
    const int orig = (d & 7) * 128 + (d >> 3);
    const int b    = orig >> 6;
    const int h0   = (orig & 63) * 2;

    #pragma unroll
    for (int p = 0; p < 2; ++p) {
        const int a_  = t + 256 * p;
        const int oc  = a_ >> 3;
        const int oct = a_ & 7;
        const float* src = wgt + (size_t)oc * 576 + (size_t)oct * 72;
        f32x4 w4[18];
        #pragma unroll
        for (int j = 0; j < 18; ++j) w4[j] = ((const f32x4*)src)[j];
        const int ch = oct >> 2, qq = oct & 3;
        const int ii = oc >> 4,  nn = oc & 15;
        #pragma unroll
        for (int kk = 0; kk < 9; ++kk) {
            #define WELEM(e) ((uint32_t)f2bf(w4[((e)*9 + kk) >> 2][((e)*9 + kk) & 3]))
            uint4 val;
            val.x = WELEM(0) | (WELEM(1) << 16);
            val.y = WELEM(2) | (WELEM(3) << 16);
            val.z = WELEM(4) | (WELEM(5) << 16);
            val.w = WELEM(6) | (WELEM(7) << 16);
            #undef WELEM
            lds[((kk * 2 + ch) * 4 + ii) * 64 + qq * 16 + nn] = val;
        }
    }

    {
        const int ic    = t >> 2;
        const int w0    = (t & 3) * 32;
        const int jslot = ic >> 3;
        const int esub  = ic & 7;
        #pragma unroll
        for (int r = 0; r < 4; ++r) {
            const int h = h0 - 1 + r;
            if (h < 0 || h >= H_) {
                uint4 z; z.x = z.y = z.z = z.w = 0;
                #pragma unroll
                for (int k = 0; k < 4; ++k)
                    lds[WLDS_U4 + r * 1024 + k * 256 + t] = z;
            } else {
                const float* src =
                    x + (((size_t)(b * C_ + ic)) * H_ + h) * W_ + w0;
                f32x4 v4[8];
                #pragma unroll
                for (int j = 0; j < 8; ++j) v4[j] = ((const f32x4*)src)[j];
                #pragma unroll
                for (int k = 0; k < 32; ++k) {
                    const int c    = w0 + k;
                    const int slot = (jslot + c) & 7;
                    lds16[WLDS_U4 * 8 + ((r * 128 + c) * 8 + slot) * 8 + esub] =
                        f2bf(v4[k >> 2][k & 3]);
                }
            }
        }
    }
    __syncthreads();

    f32x4 acc[4][4];
    #pragma unroll
    for (int i = 0; i < 4; ++i)
        #pragma unroll
        for (int tt = 0; tt < 4; ++tt)
            acc[i][tt] = (f32x4){0.f, 0.f, 0.f, 0.f};

    const int wb = (wv & 1) * 64;
    const uint4* Wl = lds;
    const uint4* Xl = lds + WLDS_U4;
    const bool lz = (wb + n) == 0;
    const bool rz = (wb + n) == 79;
    const bf16x8 zfrag = 0;

    #pragma unroll
    for (int kh = 0; kh < 3; ++kh) {
        const int row = (wv >> 1) + kh;
        #pragma unroll
        for (int kw = 0; kw < 3; ++kw) {
            const int kk = kh * 3 + kw;
            #pragma unroll
            for (int ch = 0; ch < 2; ++ch) {
                bf16x8 a[4], bb[4];
                #pragma unroll
                for (int i = 0; i < 4; ++i)
                    a[i] = __builtin_bit_cast(bf16x8,
                        Wl[((kk * 2 + ch) * 4 + i) * 64 + lane]);
                #pragma unroll
                for (int tt = 0; tt < 4; ++tt) {
                    int c   = wb + tt * 16 + n + kw - 1;
                    int cc  = min(max(c, 0), 127);
                    int idx = (row * 128 + cc) * 8 + ((ch * 4 + q + cc) & 7);
                    bf16x8 v = __builtin_bit_cast(bf16x8, Xl[idx]);
                    if (kw == 0 && tt == 0) v = lz ? zfrag : v;
                    if (kw == 2 && tt == 3) v = rz ? zfrag : v;
                    bb[tt] = v;
                }
                #pragma unroll
                for (int i = 0; i < 4; ++i)
                    #pragma unroll
                    for (int tt = 0; tt < 4; ++tt)
                        acc[i][tt] = __builtin_amdgcn_mfma_f32_16x16x32_bf16(
                            a[i], bb[tt], acc[i][tt], 0, 0, 0);
            }
        }
    }

    const int  h  = h0 + (wv >> 1);
    const bool hz = (h >= 44 && h < 84);
    #pragma unroll
    for (int i = 0; i < 4; ++i) {
        #pragma unroll
        for (int tt = 0; tt < 4; ++tt) {
            const int  w0 = wb + tt * 16 + n;
            const bool zz = hz && (w0 >= 44 && w0 < 84);
            #pragma unroll
            for (int r = 0; r < 4; ++r) {
                const int oc = i * 16 + q * 4 + r;
                out[(((size_t)b * C_ + oc) * H_ + h) * W_ + w0] =
                    zz ? 0.f : acc[i][tt][r];
            }
        }
    }
}

extern "C" void kernel_launch(void* const* d_in, const int* in_sizes, int n_in,
                              void* d_out, int out_size, void* d_ws, size_t ws_size,
                              hipStream_t stream) {
    const float* x   = (const float*)d_in[0];
    const float* wgt = (const float*)d_in[1];
    float* out       = (float*)d_out;

    const size_t W_BYTES = 9 * 2 * 4 * 64 * 16;   // 73,728
    if (ws_size >= W_BYTES) {
        uint16_t* Wb = (uint16_t*)d_ws;
        xform_weight<<<dim3(144), dim3(256), 0, stream>>>(wgt, Wb);
        conv_main<<<dim3(2048), dim3(256), 0, stream>>>(
            (const uint4*)Wb, x, out);
    } else {
        conv_fused<<<dim3(1024), dim3(256), 0, stream>>>(x, wgt, out);
    }
}